// Round 6
// baseline (95.721 us; speedup 1.0000x reference)
//
#include <hip/hip_runtime.h>

#define Bsz 64
#define Ssz 512
#define Hsz 768
#define Tsz 9
#define NCH 16
#define LOG2E 1.4426950408889634f
#define LN2F  0.6931471805599453f

#define TPB 28            // scan tasks per block (7 per wave x 4 waves)
#define WSTR 292          // em-window LDS stride (floats), padded for banks
#define MSTR 33           // mask-window LDS stride (ints)

__device__ __forceinline__ int SK(int s) { return s * Tsz + ((s >> 5) << 1); }

// ---------------- K1: emissions = enc @ fc_w^T + fc_b ----------------
// grid = B*S/16 blocks of 256. 16 lanes per position, LDS-transpose reduce.
__global__ __launch_bounds__(256) void emis_kernel(
    const float* __restrict__ x, const float* __restrict__ fcw,
    const float* __restrict__ fcb, float* __restrict__ em,
    int* __restrict__ cnt) {
    __shared__ float4 w4[Tsz * Hsz / 4];
    __shared__ float bias[Tsz];
    __shared__ float part[16 * Tsz * 16];
    const int tid = threadIdx.x;
    if (blockIdx.x == 0 && tid == 0) *cnt = 0;   // reset vit3's last-block counter
    const float4* fw4 = reinterpret_cast<const float4*>(fcw);
#pragma unroll
    for (int i = 0; i < 7; ++i) {
        const int o = tid + i * 256;
        if (o < 1728) w4[o] = fw4[o];
    }
    if (tid < Tsz) bias[tid] = fcb[tid];
    __syncthreads();

    const int p = tid >> 4, l = tid & 15;
    const float4* xr = reinterpret_cast<const float4*>(
        x + ((size_t)blockIdx.x * 16 + p) * Hsz);
    float acc[Tsz];
#pragma unroll
    for (int t = 0; t < Tsz; ++t) acc[t] = 0.0f;
#pragma unroll
    for (int i = 0; i < 12; ++i) {
        const float4 xv = xr[i * 16 + l];
#pragma unroll
        for (int t = 0; t < Tsz; ++t) {
            const float4 wv = w4[t * 192 + i * 16 + l];
            acc[t] = fmaf(xv.x, wv.x, fmaf(xv.y, wv.y,
                     fmaf(xv.z, wv.z, fmaf(xv.w, wv.w, acc[t]))));
        }
    }
#pragma unroll
    for (int t = 0; t < Tsz; ++t) part[(p * Tsz + t) * 16 + l] = acc[t];
    __syncthreads();
    if (tid < 16 * Tsz) {
        const int t = tid % Tsz;
        float s = bias[t];
#pragma unroll
        for (int l2 = 0; l2 < 16; ++l2) s += part[tid * 16 + l2];
        em[(size_t)blockIdx.x * (16 * Tsz) + tid] = s;
    }
}

// ---------------- K2: chunk transfer matrices, NO per-thread 81-arrays -------
// task tau: tau<1024 -> LSE rows of chunk bc=tau; tau>=1024 -> Viterbi rows of
// chunk bc=tau-1024. 9 lanes per task (lane = matrix row a), 7 tasks/wave,
// 28 tasks/block. E/T matrices broadcast-read from LDS.
__global__ __launch_bounds__(256, 1) void scan_kernel(
    const float* __restrict__ em, const int* __restrict__ mask,
    const float* __restrict__ trans, float* __restrict__ R2,
    float* __restrict__ MV) {
    __shared__ float win[TPB * WSTR];
    __shared__ int   mkw[TPB * MSTR];
    __shared__ float Elds[81];
    __shared__ float Tlds[81];
    const int tid = threadIdx.x;
    const int tau0 = blockIdx.x * TPB;

    if (tid < 81) {
        const float t = trans[tid];
        Tlds[tid] = t;
        Elds[tid] = exp2f(t * LOG2E);
    }
    // stage em windows (LSE tasks stored as 2^(em*log2e), VIT raw)
    for (int f = tid; f < TPB * 288; f += 256) {
        const int q = f / 288, r = f - q * 288;
        const int tau = tau0 + q;
        const int bc = (tau < 1024) ? tau : tau - 1024;
        const int b = bc >> 4, c = bc & 15;
        const int sa = c * 32 + 1 + r / 9;
        float v = 0.0f;
        if (tau < 2048 && sa < Ssz)
            v = em[(size_t)b * Ssz * Tsz + (size_t)(c * 32 + 1) * Tsz + r];
        win[q * WSTR + r] = (tau < 1024) ? exp2f(v * LOG2E) : v;
    }
    for (int f = tid; f < TPB * 32; f += 256) {
        const int q = f / 32, k = f - q * 32;
        const int tau = tau0 + q;
        const int bc = (tau < 1024) ? tau : tau - 1024;
        const int b = bc >> 4, c = bc & 15;
        const int sa = c * 32 + 1 + k;
        mkw[q * MSTR + k] = (tau < 2048 && sa < Ssz) ? mask[b * Ssz + sa] : 0;
    }
    __syncthreads();

    const int wv = tid >> 6, ln = tid & 63;
    const int q = ln / 9;                 // 0..7 (7 only for ln==63: idle)
    const int a = ln - q * 9;
    const int Q = wv * 7 + q;             // window slot in this block
    const int tau = tau0 + Q;
    if (q >= 7 || tau >= 2048) return;

    const int bc = (tau < 1024) ? tau : tau - 1024;
    const int c = bc & 15;
    const int ns = (c == 15) ? 31 : 32;
    const float* w = &win[Q * WSTR];
    const int* mk = &mkw[Q * MSTR];

    if (tau < 1024) {
        // ---- LSE rows, probability domain (replicates r3 pass1 arithmetic) ----
        float pp[Tsz];
#pragma unroll
        for (int j = 0; j < Tsz; ++j) pp[j] = (j == a) ? 1.0f : 0.0f;
        float K = 0.0f;
        for (int k = 0; k < 32; ++k) {
            if (k >= ns) break;
            const int m = mk[k];
            float g[Tsz];
#pragma unroll
            for (int j = 0; j < Tsz; ++j) g[j] = pp[0] * Elds[j];
#pragma unroll
            for (int i = 1; i < Tsz; ++i)
#pragma unroll
                for (int j = 0; j < Tsz; ++j)
                    g[j] = fmaf(pp[i], Elds[i * Tsz + j], g[j]);
#pragma unroll
            for (int j = 0; j < Tsz; ++j) {
                const float np = g[j] * w[k * Tsz + j];
                if (m > 0) pp[j] = np;
            }
            if ((k & 7) == 7) {
                float ss = 0.0f;
#pragma unroll
                for (int j = 0; j < Tsz; ++j) ss += pp[j];
                K += __log2f(ss);
                const float inv = 1.0f / ss;
#pragma unroll
                for (int j = 0; j < Tsz; ++j) pp[j] *= inv;
            }
        }
        float* o = R2 + ((size_t)tau * Tsz + a) * Tsz;
#pragma unroll
        for (int j = 0; j < Tsz; ++j) o[j] = K + __log2f(pp[j]);
    } else {
        // ---- Viterbi max-plus rows ----
        float row[Tsz];
#pragma unroll
        for (int j = 0; j < Tsz; ++j) row[j] = (j == a) ? 0.0f : -1e30f;
        for (int k = 0; k < 32; ++k) {
            if (k >= ns) break;
            const int m = mk[k];
            float g[Tsz];
#pragma unroll
            for (int j = 0; j < Tsz; ++j) g[j] = row[0] + Tlds[j];
#pragma unroll
            for (int i = 1; i < Tsz; ++i)
#pragma unroll
                for (int j = 0; j < Tsz; ++j)
                    g[j] = fmaxf(g[j], row[i] + Tlds[i * Tsz + j]);
#pragma unroll
            for (int j = 0; j < Tsz; ++j)
                if (m > 0) row[j] = g[j] + w[k * Tsz + j];
        }
        float* o = MV + (size_t)bc * 81 + a * Tsz;
#pragma unroll
        for (int j = 0; j < Tsz; ++j) o[j] = row[j];
    }
}

// first-max argmax of 9 values (strict > keeps FIRST max)
__device__ __forceinline__ void amax9(const float (&v)[Tsz], float& bv, int& bi) {
    float w01v = (v[1] > v[0]) ? v[1] : v[0]; int w01i = (v[1] > v[0]) ? 1 : 0;
    float w23v = (v[3] > v[2]) ? v[3] : v[2]; int w23i = (v[3] > v[2]) ? 3 : 2;
    float w45v = (v[5] > v[4]) ? v[5] : v[4]; int w45i = (v[5] > v[4]) ? 5 : 4;
    float w67v = (v[7] > v[6]) ? v[7] : v[6]; int w67i = (v[7] > v[6]) ? 7 : 6;
    float x03v = (w23v > w01v) ? w23v : w01v; int x03i = (w23v > w01v) ? w23i : w01i;
    float x47v = (w67v > w45v) ? w67v : w45v; int x47i = (w67v > w45v) ? w67i : w45i;
    float y07v = (x47v > x03v) ? x47v : x03v; int y07i = (x47v > x03v) ? x47i : x03i;
    bv = (v[8] > y07v) ? v[8] : y07v;
    bi = (v[8] > y07v) ? 8 : y07i;
}

// ============ K3: per-batch finish + fused final reduce (last block) ============
__global__ __launch_bounds__(192, 1) void vit3_kernel(
    const float* __restrict__ em, const int* __restrict__ labels,
    const int* __restrict__ mask, const int* __restrict__ lengths,
    const float* __restrict__ start_t, const float* __restrict__ end_t,
    const float* __restrict__ trans, const float* __restrict__ R2,
    const float* __restrict__ MV, float* __restrict__ out_path,
    float* __restrict__ ll, float* __restrict__ dout, int* __restrict__ cnt) {
    __shared__ __align__(16) float em_s[4640];          // skewed [s][j]
    __shared__ __align__(16) int   mk_s[Ssz];
    __shared__ __align__(16) float mv_s[NCH * 81];
    __shared__ __align__(16) float r2_s[NCH * 81];
    __shared__ float tr_s[81];
    __shared__ float st_s[12], en_s[12];
    __shared__ __align__(16) float alc[2][NCH][12];
    __shared__ float a2c[2][12];
    __shared__ unsigned char bp[(Ssz - 1) * Tsz];
    __shared__ unsigned char mapA[64][12], mapB[64][12];
    __shared__ float den_sh, num_sh;
    __shared__ int lastf;

    const int b = blockIdx.x, tid = threadIdx.x;
    const int wv = tid >> 6, ln = tid & 63;
    const int c = tid / 12, j9 = tid % 12;
    const float* emb = em + (size_t)b * Ssz * Tsz;
    const int* mkb = mask + b * Ssz;
    const int* lbb = labels + b * Ssz;

    // ---- staging ----
    for (int i = tid; i < Ssz * Tsz; i += 192) {
        const int s = i / 9, j = i - s * 9;
        em_s[SK(s) + j] = emb[i];
    }
    for (int i = tid; i < Ssz; i += 192) mk_s[i] = mkb[i];
    {
        const float4* v4 = reinterpret_cast<const float4*>(MV + (size_t)b * NCH * 81);
        float4* vd = reinterpret_cast<float4*>(mv_s);
        for (int i = tid; i < NCH * 81 / 4; i += 192) vd[i] = v4[i];
        const float4* r4 = reinterpret_cast<const float4*>(R2 + (size_t)b * NCH * 81);
        float4* rd = reinterpret_cast<float4*>(r2_s);
        for (int i = tid; i < NCH * 81 / 4; i += 192) rd[i] = r4[i];
        if (tid < 81) tr_s[tid] = trans[tid];
        if (tid >= 96 && tid < 96 + Tsz) {
            st_s[tid - 96] = start_t[tid - 96];
            en_s[tid - 96] = end_t[tid - 96];
        }
    }
    __syncthreads();

    float tc[Tsz];
    const int jj = (j9 < Tsz) ? j9 : Tsz - 1;
#pragma unroll
    for (int i = 0; i < Tsz; ++i) tc[i] = tr_s[i * Tsz + jj];

    float aj = 0.0f;
    if (c == 0 && j9 < Tsz) {
        aj = st_s[j9] + em_s[j9];
        alc[0][0][j9] = aj;
    }
    if (wv == 1 && ln < Tsz) a2c[0][ln] = (st_s[ln] + em_s[ln]) * LOG2E;

    // ---- phase A: vit prefix chain + den combine chain (16 rounds) ----
    for (int r = 0; r < NCH; ++r) {
        __syncthreads();
        if (r < NCH - 1 && c == r + 1 && j9 < Tsz) {
            const float* M = &mv_s[r * 81];
            float m = alc[0][r][0] + M[j9];
#pragma unroll
            for (int i = 1; i < Tsz; ++i)
                m = fmaxf(m, alc[0][r][i] + M[i * Tsz + j9]);
            aj = m;
            alc[0][c][j9] = m;
        }
        if (wv == 1 && ln < Tsz) {
            const float* Rr = &r2_s[r * 81];
            float xi[Tsz];
#pragma unroll
            for (int i = 0; i < Tsz; ++i) xi[i] = a2c[r & 1][i] + Rr[i * Tsz + ln];
            float m = xi[0];
#pragma unroll
            for (int i = 1; i < Tsz; ++i) m = fmaxf(m, xi[i]);
            float sm = 0.0f;
#pragma unroll
            for (int i = 0; i < Tsz; ++i) sm += exp2f(xi[i] - m);
            a2c[(r + 1) & 1][ln] = m + __log2f(sm);
        }
    }

    // ---- phase B: chunk-parallel viterbi scan (32 barrier-steps) ----
    int pb = 0;
    for (int k = 0; k < 32; ++k) {
        __syncthreads();
        const int s = c * 32 + 1 + k;
        if (j9 < Tsz && s <= Ssz - 1) {
            const int mk = mk_s[s];
            float av[12];
            const float4* ap = reinterpret_cast<const float4*>(&alc[pb][c][0]);
            *reinterpret_cast<float4*>(&av[0]) = ap[0];
            *reinterpret_cast<float4*>(&av[4]) = ap[1];
            *reinterpret_cast<float4*>(&av[8]) = ap[2];
            float v[Tsz];
#pragma unroll
            for (int i = 0; i < Tsz; ++i) v[i] = av[i] + tc[i];
            float bv; int bi;
            amax9(v, bv, bi);
            bp[(s - 1) * Tsz + j9] = (unsigned char)((mk > 0) ? bi : j9);
            if (mk > 0) aj = bv + em_s[SK(s) + j9];
        }
        if (j9 < Tsz) alc[1 - pb][c][j9] = aj;
        pb ^= 1;
    }
    __syncthreads();

    // ---- last tag (redundant per-thread) ----
    float bb = alc[0][NCH - 1][0] + en_s[0];
    int last = 0;
#pragma unroll
    for (int q = 1; q < Tsz; ++q) {
        const float qq = alc[0][NCH - 1][q] + en_s[q];
        if (qq > bb) { bb = qq; last = q; }
    }

    // ---- S1: wave0 chunk maps, wave1 den final, wave2 numerator ----
    const int lo = ln * 8;
    const int hi = min(lo + 7, Ssz - 2);
    if (wv == 0) {
        int xf[Tsz];
#pragma unroll
        for (int t = 0; t < Tsz; ++t) xf[t] = t;
        for (int k = hi; k >= lo; --k) {
#pragma unroll
            for (int t = 0; t < Tsz; ++t) xf[t] = bp[k * Tsz + xf[t]];
        }
#pragma unroll
        for (int t = 0; t < Tsz; ++t) mapA[ln][t] = (unsigned char)xf[t];
    } else if (wv == 1) {
        if (ln == 0) {
            float xv[Tsz];
#pragma unroll
            for (int i = 0; i < Tsz; ++i) xv[i] = a2c[0][i] + en_s[i] * LOG2E;
            float m = xv[0];
#pragma unroll
            for (int i = 1; i < Tsz; ++i) m = fmaxf(m, xv[i]);
            float sm = 0.0f;
#pragma unroll
            for (int i = 0; i < Tsz; ++i) sm += exp2f(xv[i] - m);
            den_sh = m + __log2f(sm);
        }
    } else {
        float part = 0.0f;
        for (int s = 1 + ln; s < Ssz; s += 64) {
            if (mk_s[s] > 0) {
                const int tg = lbb[s];
                int pq = s - 1;
                while (pq > 0 && mk_s[pq] == 0) --pq;
                part += tr_s[lbb[pq] * Tsz + tg] + em_s[SK(s) + tg];
            }
        }
#pragma unroll
        for (int off = 32; off >= 1; off >>= 1) part += __shfl_xor(part, off, 64);
        if (ln == 0) {
            const int tg0 = lbb[0];
            float num = part + st_s[tg0] + em_s[tg0];
            int pq = Ssz - 1;
            while (pq > 0 && mk_s[pq] == 0) --pq;
            num += en_s[lbb[pq]];
            num_sh = num;
        }
    }

    // ---- suffix-composition doubling ----
#define VIT_RND(CUR, NXT, D)                                               \
    {                                                                      \
        unsigned char nn[Tsz];                                             \
        if (wv == 0) {                                                     \
            const int o = ln + (D);                                        \
            if (o < 64) {                                                  \
                _Pragma("unroll") for (int t = 0; t < Tsz; ++t)            \
                    nn[t] = CUR[ln][CUR[o][t]];                            \
            } else {                                                       \
                _Pragma("unroll") for (int t = 0; t < Tsz; ++t)            \
                    nn[t] = CUR[ln][t];                                    \
            }                                                              \
        }                                                                  \
        __syncthreads();                                                   \
        if (wv == 0) {                                                     \
            _Pragma("unroll") for (int t = 0; t < Tsz; ++t)                \
                NXT[ln][t] = nn[t];                                        \
        }                                                                  \
        __syncthreads();                                                   \
    }
    VIT_RND(mapA, mapB, 1)
    VIT_RND(mapB, mapA, 2)
    VIT_RND(mapA, mapB, 4)
    VIT_RND(mapB, mapA, 8)
    VIT_RND(mapA, mapB, 16)
    VIT_RND(mapB, mapA, 32)
#undef VIT_RND

    if (wv == 0) {
        int t = (ln == 63) ? last : (int)mapA[ln + 1][last];
        float* op = out_path + (size_t)b * Ssz;
        for (int k = hi; k >= lo; --k) {
            t = bp[k * Tsz + t];
            op[k] = (float)t;
        }
        if (ln == 0) op[Ssz - 1] = (float)last;
    }
    if (b == 0 && wv == 2) dout[1 + Bsz * Ssz + ln] = (float)lengths[ln];

    // ---- fused final reduce: last block sums ll -> loss ----
    if (tid == 0) {
        ll[b] = num_sh - den_sh * LN2F;
        __threadfence();
        lastf = (atomicAdd(cnt, 1) == Bsz - 1) ? 1 : 0;
    }
    __syncthreads();
    if (lastf && wv == 0) {
        __threadfence();
        float v = ll[ln];
#pragma unroll
        for (int off = 32; off >= 1; off >>= 1) v += __shfl_xor(v, off, 64);
        if (ln == 0) dout[0] = -v * (1.0f / (float)Bsz);
    }
}

extern "C" void kernel_launch(void* const* d_in, const int* in_sizes, int n_in,
                              void* d_out, int out_size, void* d_ws, size_t ws_size,
                              hipStream_t stream) {
    const float* enc    = (const float*)d_in[0];
    const int*   labels = (const int*)d_in[1];
    const int*   mask   = (const int*)d_in[2];
    const int*   lengths= (const int*)d_in[3];
    const float* fcw    = (const float*)d_in[4];
    const float* fcb    = (const float*)d_in[5];
    const float* startt = (const float*)d_in[6];
    const float* endt   = (const float*)d_in[7];
    const float* trans  = (const float*)d_in[8];

    float* out = (float*)d_out;
    float* em  = (float*)d_ws;                                // 294912 f
    float* R2  = em + (size_t)Bsz * Ssz * Tsz;                // 82944 f
    float* MV  = R2 + (size_t)Bsz * NCH * 81;                 // 82944 f
    float* ll  = MV + (size_t)Bsz * NCH * 81;                 // 64 f
    int*   cnt = (int*)(ll + Bsz);                            // 1 int

    emis_kernel<<<Bsz * Ssz / 16, 256, 0, stream>>>(enc, fcw, fcb, em, cnt);
    scan_kernel<<<(2 * Bsz * NCH + TPB - 1) / TPB, 256, 0, stream>>>(
        em, mask, trans, R2, MV);
    vit3_kernel<<<Bsz, 192, 0, stream>>>(em, labels, mask, lengths, startt, endt,
                                         trans, R2, MV, out + 1, ll, out, cnt);
}

// Round 7
// 94.741 us; speedup vs baseline: 1.0103x; 1.0103x over previous
//
#include <hip/hip_runtime.h>

#define Bsz 64
#define Ssz 512
#define Hsz 768
#define Tsz 9
#define NCH 16
#define LOG2E 1.4426950408889634f
#define LN2F  0.6931471805599453f

#define TPB 28            // scan tasks per block (7 per wave x 4 waves)
#define WSTR 292          // em-window LDS stride (floats), padded for banks
#define MSTR 33           // mask-window LDS stride (ints)
#define PSTR 17           // emis partial-reduce stride (bank-conflict-free read)

__device__ __forceinline__ int SK(int s) { return s * Tsz + ((s >> 5) << 1); }

// ---------------- K1: emissions = enc @ fc_w^T + fc_b ----------------
// grid = B*S/64 = 512 blocks of 256. 16 lanes/position, 4 positions/thread:
// each w-tile ds_read_b128 is reused 4x -> LDS pipe no longer the bottleneck.
__global__ __launch_bounds__(256) void emis_kernel(
    const float* __restrict__ x, const float* __restrict__ fcw,
    const float* __restrict__ fcb, float* __restrict__ em,
    int* __restrict__ cnt) {
    __shared__ float4 w4[Tsz * Hsz / 4];          // 27648 B
    __shared__ float bias[Tsz];
    __shared__ float part[16 * Tsz * PSTR];       // 2448 floats
    const int tid = threadIdx.x;
    if (blockIdx.x == 0 && tid == 0) *cnt = 0;    // reset vit3's counter
    const float4* fw4 = reinterpret_cast<const float4*>(fcw);
#pragma unroll
    for (int i = 0; i < 7; ++i) {
        const int o = tid + i * 256;
        if (o < 1728) w4[o] = fw4[o];
    }
    if (tid < Tsz) bias[tid] = fcb[tid];
    __syncthreads();

    const int p = tid >> 4, l = tid & 15;
    const size_t pos0 = (size_t)blockIdx.x * 64;
    const float4* xr0 = reinterpret_cast<const float4*>(x + (pos0 + p) * Hsz);
    const float4* xr1 = reinterpret_cast<const float4*>(x + (pos0 + p + 16) * Hsz);
    const float4* xr2 = reinterpret_cast<const float4*>(x + (pos0 + p + 32) * Hsz);
    const float4* xr3 = reinterpret_cast<const float4*>(x + (pos0 + p + 48) * Hsz);

    float acc[Tsz][4];
#pragma unroll
    for (int t = 0; t < Tsz; ++t)
#pragma unroll
        for (int q = 0; q < 4; ++q) acc[t][q] = 0.0f;

#pragma unroll 4
    for (int i = 0; i < 12; ++i) {
        const float4 xv0 = xr0[i * 16 + l];
        const float4 xv1 = xr1[i * 16 + l];
        const float4 xv2 = xr2[i * 16 + l];
        const float4 xv3 = xr3[i * 16 + l];
#pragma unroll
        for (int t = 0; t < Tsz; ++t) {
            const float4 wv = w4[t * 192 + i * 16 + l];
            acc[t][0] = fmaf(xv0.x, wv.x, fmaf(xv0.y, wv.y,
                        fmaf(xv0.z, wv.z, fmaf(xv0.w, wv.w, acc[t][0]))));
            acc[t][1] = fmaf(xv1.x, wv.x, fmaf(xv1.y, wv.y,
                        fmaf(xv1.z, wv.z, fmaf(xv1.w, wv.w, acc[t][1]))));
            acc[t][2] = fmaf(xv2.x, wv.x, fmaf(xv2.y, wv.y,
                        fmaf(xv2.z, wv.z, fmaf(xv2.w, wv.w, acc[t][2]))));
            acc[t][3] = fmaf(xv3.x, wv.x, fmaf(xv3.y, wv.y,
                        fmaf(xv3.z, wv.z, fmaf(xv3.w, wv.w, acc[t][3]))));
        }
    }

#pragma unroll
    for (int pb = 0; pb < 4; ++pb) {            // pb compile-time (rule #20)
        __syncthreads();
#pragma unroll
        for (int t = 0; t < Tsz; ++t) part[(p * Tsz + t) * PSTR + l] = acc[t][pb];
        __syncthreads();
        if (tid < 16 * Tsz) {
            const int pp = tid / Tsz, t = tid - pp * Tsz;
            float s = bias[t];
#pragma unroll
            for (int l2 = 0; l2 < 16; ++l2) s += part[(pp * Tsz + t) * PSTR + l2];
            em[(pos0 + pb * 16 + pp) * Tsz + t] = s;
        }
    }
}

// ---------------- K2: chunk transfer matrices --------------------------------
// task tau: tau<1024 -> LSE rows of chunk bc=tau; tau>=1024 -> Viterbi rows of
// chunk bc=tau-1024. 9 lanes per task (lane = matrix row a), 7 tasks/wave.
// E/T kept in registers as NINE float[9] arrays (token-pasted literal indices)
// so SROA promotes them -- the 81-element-array scratch disease is the single
// cause of every slow scan so far.
__global__ __launch_bounds__(256, 1) void scan_kernel(
    const float* __restrict__ em, const int* __restrict__ mask,
    const float* __restrict__ trans, float* __restrict__ R2,
    float* __restrict__ MV) {
    __shared__ float win[TPB * WSTR];
    __shared__ int   mkw[TPB * MSTR];
    __shared__ float Elds[81];
    __shared__ float Tlds[81];
    const int tid = threadIdx.x;
    const int tau0 = blockIdx.x * TPB;

    if (tid < 81) {
        const float t = trans[tid];
        Tlds[tid] = t;
        Elds[tid] = exp2f(t * LOG2E);
    }
    for (int f = tid; f < TPB * 288; f += 256) {
        const int q = f / 288, r = f - q * 288;
        const int tau = tau0 + q;
        const int bc = (tau < 1024) ? tau : tau - 1024;
        const int b = bc >> 4, c = bc & 15;
        const int sa = c * 32 + 1 + r / 9;
        float v = 0.0f;
        if (tau < 2048 && sa < Ssz)
            v = em[(size_t)b * Ssz * Tsz + (size_t)(c * 32 + 1) * Tsz + r];
        win[q * WSTR + r] = (tau < 1024) ? exp2f(v * LOG2E) : v;
    }
    for (int f = tid; f < TPB * 32; f += 256) {
        const int q = f / 32, k = f - q * 32;
        const int tau = tau0 + q;
        const int bc = (tau < 1024) ? tau : tau - 1024;
        const int b = bc >> 4, c = bc & 15;
        const int sa = c * 32 + 1 + k;
        mkw[q * MSTR + k] = (tau < 2048 && sa < Ssz) ? mask[b * Ssz + sa] : 0;
    }
    __syncthreads();

    const int wv = tid >> 6, ln = tid & 63;
    const int q = ln / 9;
    const int a = ln - q * 9;
    const int Q = wv * 7 + q;
    const int tau = tau0 + Q;
    if (q >= 7 || tau >= 2048) return;

    const int bc = (tau < 1024) ? tau : tau - 1024;
    const int c = bc & 15;
    const int ns = (c == 15) ? 31 : 32;
    const float* w = &win[Q * WSTR];
    const int* mk = &mkw[Q * MSTR];

    if (tau < 1024) {
        // ---- LSE rows, probability domain (identical arithmetic to r3/r6) ----
#define DECL_E(ii) float E##ii[Tsz];                                       \
        _Pragma("unroll") for (int j = 0; j < Tsz; ++j)                    \
            E##ii[j] = Elds[ii * Tsz + j];
        DECL_E(0) DECL_E(1) DECL_E(2) DECL_E(3) DECL_E(4)
        DECL_E(5) DECL_E(6) DECL_E(7) DECL_E(8)
#undef DECL_E
        float pp[Tsz];
#pragma unroll
        for (int j = 0; j < Tsz; ++j) pp[j] = (j == a) ? 1.0f : 0.0f;
        float K = 0.0f;
        for (int k = 0; k < 32; ++k) {
            if (k >= ns) break;
            const int m = mk[k];
            float g[Tsz];
#pragma unroll
            for (int j = 0; j < Tsz; ++j) g[j] = pp[0] * E0[j];
#define FROW(ii)                                                           \
            _Pragma("unroll") for (int j = 0; j < Tsz; ++j)                \
                g[j] = fmaf(pp[ii], E##ii[j], g[j]);
            FROW(1) FROW(2) FROW(3) FROW(4) FROW(5) FROW(6) FROW(7) FROW(8)
#undef FROW
#pragma unroll
            for (int j = 0; j < Tsz; ++j) {
                const float np = g[j] * w[k * Tsz + j];
                if (m > 0) pp[j] = np;
            }
            if ((k & 7) == 7) {
                float ss = 0.0f;
#pragma unroll
                for (int j = 0; j < Tsz; ++j) ss += pp[j];
                K += __log2f(ss);
                const float inv = 1.0f / ss;
#pragma unroll
                for (int j = 0; j < Tsz; ++j) pp[j] *= inv;
            }
        }
        float* o = R2 + ((size_t)tau * Tsz + a) * Tsz;
#pragma unroll
        for (int j = 0; j < Tsz; ++j) o[j] = K + __log2f(pp[j]);
    } else {
        // ---- Viterbi max-plus rows ----
#define DECL_T(ii) float T##ii[Tsz];                                       \
        _Pragma("unroll") for (int j = 0; j < Tsz; ++j)                    \
            T##ii[j] = Tlds[ii * Tsz + j];
        DECL_T(0) DECL_T(1) DECL_T(2) DECL_T(3) DECL_T(4)
        DECL_T(5) DECL_T(6) DECL_T(7) DECL_T(8)
#undef DECL_T
        float row[Tsz];
#pragma unroll
        for (int j = 0; j < Tsz; ++j) row[j] = (j == a) ? 0.0f : -1e30f;
        for (int k = 0; k < 32; ++k) {
            if (k >= ns) break;
            const int m = mk[k];
            float g[Tsz];
#pragma unroll
            for (int j = 0; j < Tsz; ++j) g[j] = row[0] + T0[j];
#define MROW(ii)                                                           \
            _Pragma("unroll") for (int j = 0; j < Tsz; ++j)                \
                g[j] = fmaxf(g[j], row[ii] + T##ii[j]);
            MROW(1) MROW(2) MROW(3) MROW(4) MROW(5) MROW(6) MROW(7) MROW(8)
#undef MROW
#pragma unroll
            for (int j = 0; j < Tsz; ++j)
                if (m > 0) row[j] = g[j] + w[k * Tsz + j];
        }
        float* o = MV + (size_t)bc * 81 + a * Tsz;
#pragma unroll
        for (int j = 0; j < Tsz; ++j) o[j] = row[j];
    }
}

// first-max argmax of 9 values (strict > keeps FIRST max)
__device__ __forceinline__ void amax9(const float (&v)[Tsz], float& bv, int& bi) {
    float w01v = (v[1] > v[0]) ? v[1] : v[0]; int w01i = (v[1] > v[0]) ? 1 : 0;
    float w23v = (v[3] > v[2]) ? v[3] : v[2]; int w23i = (v[3] > v[2]) ? 3 : 2;
    float w45v = (v[5] > v[4]) ? v[5] : v[4]; int w45i = (v[5] > v[4]) ? 5 : 4;
    float w67v = (v[7] > v[6]) ? v[7] : v[6]; int w67i = (v[7] > v[6]) ? 7 : 6;
    float x03v = (w23v > w01v) ? w23v : w01v; int x03i = (w23v > w01v) ? w23i : w01i;
    float x47v = (w67v > w45v) ? w67v : w45v; int x47i = (w67v > w45v) ? w67i : w45i;
    float y07v = (x47v > x03v) ? x47v : x03v; int y07i = (x47v > x03v) ? x47i : x03i;
    bv = (v[8] > y07v) ? v[8] : y07v;
    bi = (v[8] > y07v) ? 8 : y07i;
}

// ============ K3: per-batch finish + fused final reduce (last block) ============
__global__ __launch_bounds__(192, 1) void vit3_kernel(
    const float* __restrict__ em, const int* __restrict__ labels,
    const int* __restrict__ mask, const int* __restrict__ lengths,
    const float* __restrict__ start_t, const float* __restrict__ end_t,
    const float* __restrict__ trans, const float* __restrict__ R2,
    const float* __restrict__ MV, float* __restrict__ out_path,
    float* __restrict__ ll, float* __restrict__ dout, int* __restrict__ cnt) {
    __shared__ __align__(16) float em_s[4640];          // skewed [s][j]
    __shared__ __align__(16) int   mk_s[Ssz];
    __shared__ __align__(16) float mv_s[NCH * 81];
    __shared__ __align__(16) float r2_s[NCH * 81];
    __shared__ float tr_s[81];
    __shared__ float st_s[12], en_s[12];
    __shared__ __align__(16) float alc[2][NCH][12];
    __shared__ float a2c[2][12];
    __shared__ unsigned char bp[(Ssz - 1) * Tsz];
    __shared__ unsigned char mapA[64][12], mapB[64][12];
    __shared__ float den_sh, num_sh;
    __shared__ int lastf;

    const int b = blockIdx.x, tid = threadIdx.x;
    const int wv = tid >> 6, ln = tid & 63;
    const int c = tid / 12, j9 = tid % 12;
    const float* emb = em + (size_t)b * Ssz * Tsz;
    const int* mkb = mask + b * Ssz;
    const int* lbb = labels + b * Ssz;

    // ---- staging ----
    for (int i = tid; i < Ssz * Tsz; i += 192) {
        const int s = i / 9, j = i - s * 9;
        em_s[SK(s) + j] = emb[i];
    }
    for (int i = tid; i < Ssz; i += 192) mk_s[i] = mkb[i];
    {
        const float4* v4 = reinterpret_cast<const float4*>(MV + (size_t)b * NCH * 81);
        float4* vd = reinterpret_cast<float4*>(mv_s);
        for (int i = tid; i < NCH * 81 / 4; i += 192) vd[i] = v4[i];
        const float4* r4 = reinterpret_cast<const float4*>(R2 + (size_t)b * NCH * 81);
        float4* rd = reinterpret_cast<float4*>(r2_s);
        for (int i = tid; i < NCH * 81 / 4; i += 192) rd[i] = r4[i];
        if (tid < 81) tr_s[tid] = trans[tid];
        if (tid >= 96 && tid < 96 + Tsz) {
            st_s[tid - 96] = start_t[tid - 96];
            en_s[tid - 96] = end_t[tid - 96];
        }
    }
    __syncthreads();

    float tc[Tsz];
    const int jj = (j9 < Tsz) ? j9 : Tsz - 1;
#pragma unroll
    for (int i = 0; i < Tsz; ++i) tc[i] = tr_s[i * Tsz + jj];

    float aj = 0.0f;
    if (c == 0 && j9 < Tsz) {
        aj = st_s[j9] + em_s[j9];
        alc[0][0][j9] = aj;
    }
    if (wv == 1 && ln < Tsz) a2c[0][ln] = (st_s[ln] + em_s[ln]) * LOG2E;

    // ---- phase A: vit prefix chain + den combine chain (16 rounds) ----
    for (int r = 0; r < NCH; ++r) {
        __syncthreads();
        if (r < NCH - 1 && c == r + 1 && j9 < Tsz) {
            const float* M = &mv_s[r * 81];
            float m = alc[0][r][0] + M[j9];
#pragma unroll
            for (int i = 1; i < Tsz; ++i)
                m = fmaxf(m, alc[0][r][i] + M[i * Tsz + j9]);
            aj = m;
            alc[0][c][j9] = m;
        }
        if (wv == 1 && ln < Tsz) {
            const float* Rr = &r2_s[r * 81];
            float xi[Tsz];
#pragma unroll
            for (int i = 0; i < Tsz; ++i) xi[i] = a2c[r & 1][i] + Rr[i * Tsz + ln];
            float m = xi[0];
#pragma unroll
            for (int i = 1; i < Tsz; ++i) m = fmaxf(m, xi[i]);
            float sm = 0.0f;
#pragma unroll
            for (int i = 0; i < Tsz; ++i) sm += exp2f(xi[i] - m);
            a2c[(r + 1) & 1][ln] = m + __log2f(sm);
        }
    }

    // ---- phase B: chunk-parallel viterbi scan (32 barrier-steps) ----
    int pb = 0;
    for (int k = 0; k < 32; ++k) {
        __syncthreads();
        const int s = c * 32 + 1 + k;
        if (j9 < Tsz && s <= Ssz - 1) {
            const int mk = mk_s[s];
            float av[12];
            const float4* ap = reinterpret_cast<const float4*>(&alc[pb][c][0]);
            *reinterpret_cast<float4*>(&av[0]) = ap[0];
            *reinterpret_cast<float4*>(&av[4]) = ap[1];
            *reinterpret_cast<float4*>(&av[8]) = ap[2];
            float v[Tsz];
#pragma unroll
            for (int i = 0; i < Tsz; ++i) v[i] = av[i] + tc[i];
            float bv; int bi;
            amax9(v, bv, bi);
            bp[(s - 1) * Tsz + j9] = (unsigned char)((mk > 0) ? bi : j9);
            if (mk > 0) aj = bv + em_s[SK(s) + j9];
        }
        if (j9 < Tsz) alc[1 - pb][c][j9] = aj;
        pb ^= 1;
    }
    __syncthreads();

    // ---- last tag (redundant per-thread) ----
    float bb = alc[0][NCH - 1][0] + en_s[0];
    int last = 0;
#pragma unroll
    for (int q = 1; q < Tsz; ++q) {
        const float qq = alc[0][NCH - 1][q] + en_s[q];
        if (qq > bb) { bb = qq; last = q; }
    }

    // ---- S1: wave0 chunk maps, wave1 den final, wave2 numerator ----
    const int lo = ln * 8;
    const int hi = min(lo + 7, Ssz - 2);
    if (wv == 0) {
        int xf[Tsz];
#pragma unroll
        for (int t = 0; t < Tsz; ++t) xf[t] = t;
        for (int k = hi; k >= lo; --k) {
#pragma unroll
            for (int t = 0; t < Tsz; ++t) xf[t] = bp[k * Tsz + xf[t]];
        }
#pragma unroll
        for (int t = 0; t < Tsz; ++t) mapA[ln][t] = (unsigned char)xf[t];
    } else if (wv == 1) {
        if (ln == 0) {
            float xv[Tsz];
#pragma unroll
            for (int i = 0; i < Tsz; ++i) xv[i] = a2c[0][i] + en_s[i] * LOG2E;
            float m = xv[0];
#pragma unroll
            for (int i = 1; i < Tsz; ++i) m = fmaxf(m, xv[i]);
            float sm = 0.0f;
#pragma unroll
            for (int i = 0; i < Tsz; ++i) sm += exp2f(xv[i] - m);
            den_sh = m + __log2f(sm);
        }
    } else {
        float part = 0.0f;
        for (int s = 1 + ln; s < Ssz; s += 64) {
            if (mk_s[s] > 0) {
                const int tg = lbb[s];
                int pq = s - 1;
                while (pq > 0 && mk_s[pq] == 0) --pq;
                part += tr_s[lbb[pq] * Tsz + tg] + em_s[SK(s) + tg];
            }
        }
#pragma unroll
        for (int off = 32; off >= 1; off >>= 1) part += __shfl_xor(part, off, 64);
        if (ln == 0) {
            const int tg0 = lbb[0];
            float num = part + st_s[tg0] + em_s[tg0];
            int pq = Ssz - 1;
            while (pq > 0 && mk_s[pq] == 0) --pq;
            num += en_s[lbb[pq]];
            num_sh = num;
        }
    }

    // ---- suffix-composition doubling ----
#define VIT_RND(CUR, NXT, D)                                               \
    {                                                                      \
        unsigned char nn[Tsz];                                             \
        if (wv == 0) {                                                     \
            const int o = ln + (D);                                        \
            if (o < 64) {                                                  \
                _Pragma("unroll") for (int t = 0; t < Tsz; ++t)            \
                    nn[t] = CUR[ln][CUR[o][t]];                            \
            } else {                                                       \
                _Pragma("unroll") for (int t = 0; t < Tsz; ++t)            \
                    nn[t] = CUR[ln][t];                                    \
            }                                                              \
        }                                                                  \
        __syncthreads();                                                   \
        if (wv == 0) {                                                     \
            _Pragma("unroll") for (int t = 0; t < Tsz; ++t)                \
                NXT[ln][t] = nn[t];                                        \
        }                                                                  \
        __syncthreads();                                                   \
    }
    VIT_RND(mapA, mapB, 1)
    VIT_RND(mapB, mapA, 2)
    VIT_RND(mapA, mapB, 4)
    VIT_RND(mapB, mapA, 8)
    VIT_RND(mapA, mapB, 16)
    VIT_RND(mapB, mapA, 32)
#undef VIT_RND

    if (wv == 0) {
        int t = (ln == 63) ? last : (int)mapA[ln + 1][last];
        float* op = out_path + (size_t)b * Ssz;
        for (int k = hi; k >= lo; --k) {
            t = bp[k * Tsz + t];
            op[k] = (float)t;
        }
        if (ln == 0) op[Ssz - 1] = (float)last;
    }
    if (b == 0 && wv == 2) dout[1 + Bsz * Ssz + ln] = (float)lengths[ln];

    // ---- fused final reduce: last block sums ll -> loss ----
    if (tid == 0) {
        ll[b] = num_sh - den_sh * LN2F;
        __threadfence();
        lastf = (atomicAdd(cnt, 1) == Bsz - 1) ? 1 : 0;
    }
    __syncthreads();
    if (lastf && wv == 0) {
        __threadfence();
        float v = ll[ln];
#pragma unroll
        for (int off = 32; off >= 1; off >>= 1) v += __shfl_xor(v, off, 64);
        if (ln == 0) dout[0] = -v * (1.0f / (float)Bsz);
    }
}

extern "C" void kernel_launch(void* const* d_in, const int* in_sizes, int n_in,
                              void* d_out, int out_size, void* d_ws, size_t ws_size,
                              hipStream_t stream) {
    const float* enc    = (const float*)d_in[0];
    const int*   labels = (const int*)d_in[1];
    const int*   mask   = (const int*)d_in[2];
    const int*   lengths= (const int*)d_in[3];
    const float* fcw    = (const float*)d_in[4];
    const float* fcb    = (const float*)d_in[5];
    const float* startt = (const float*)d_in[6];
    const float* endt   = (const float*)d_in[7];
    const float* trans  = (const float*)d_in[8];

    float* out = (float*)d_out;
    float* em  = (float*)d_ws;                                // 294912 f
    float* R2  = em + (size_t)Bsz * Ssz * Tsz;                // 82944 f
    float* MV  = R2 + (size_t)Bsz * NCH * 81;                 // 82944 f
    float* ll  = MV + (size_t)Bsz * NCH * 81;                 // 64 f
    int*   cnt = (int*)(ll + Bsz);                            // 1 int

    emis_kernel<<<Bsz * Ssz / 64, 256, 0, stream>>>(enc, fcw, fcb, em, cnt);
    scan_kernel<<<(2 * Bsz * NCH + TPB - 1) / TPB, 256, 0, stream>>>(
        em, mask, trans, R2, MV);
    vit3_kernel<<<Bsz, 192, 0, stream>>>(em, labels, mask, lengths, startt, endt,
                                         trans, R2, MV, out + 1, ll, out, cnt);
}

// Round 8
// 76.845 us; speedup vs baseline: 1.2456x; 1.2329x over previous
//
#include <hip/hip_runtime.h>

#define Bsz 64
#define Ssz 512
#define Hsz 768
#define Tsz 9
#define NCH 16
#define LOG2E 1.4426950408889634f
#define LN2F  0.6931471805599453f
#define PSTR 17

__device__ __forceinline__ int SK(int s) { return s * Tsz + ((s >> 5) << 1); }

// ---------------- K1: emissions = enc @ fc_w^T + fc_b ----------------
// 256 blocks x 256 threads; thread (p,l) computes H-slice l for 8 positions
// (pos0 + k*16 + p). Each w-tile ds_read feeds 8 positions -> LDS pipe is
// no longer the bound (was 8 blocks/CU x 864 ds_read_b128 x 12cy = 35us).
__global__ __launch_bounds__(256, 1) void emis_kernel(
    const float* __restrict__ x, const float* __restrict__ fcw,
    const float* __restrict__ fcb, float* __restrict__ em,
    int* __restrict__ cnt) {
    __shared__ __align__(16) float4 w4[Tsz * Hsz / 4];   // 27648 B
    __shared__ float bias[Tsz];
    __shared__ float part[16 * Tsz * PSTR];
    const int tid = threadIdx.x;
    if (blockIdx.x == 0 && tid == 0) *cnt = 0;           // vit3's reduce counter
    const float4* fw4 = reinterpret_cast<const float4*>(fcw);
#pragma unroll
    for (int i = 0; i < 7; ++i) {
        const int o = tid + i * 256;
        if (o < 1728) w4[o] = fw4[o];
    }
    if (tid < Tsz) bias[tid] = fcb[tid];
    __syncthreads();

    const int p = tid >> 4, l = tid & 15;
    const size_t pos0 = (size_t)blockIdx.x * 128;

    const float4* xr[8];
#pragma unroll
    for (int k = 0; k < 8; ++k)
        xr[k] = reinterpret_cast<const float4*>(x + (pos0 + (size_t)k * 16 + p) * Hsz);

    float acc[Tsz][8];
#pragma unroll
    for (int t = 0; t < Tsz; ++t)
#pragma unroll
        for (int k = 0; k < 8; ++k) acc[t][k] = 0.0f;

#pragma unroll 2
    for (int i = 0; i < 12; ++i) {
        float4 xv[8];
#pragma unroll
        for (int k = 0; k < 8; ++k) xv[k] = xr[k][i * 16 + l];
#pragma unroll
        for (int t = 0; t < Tsz; ++t) {
            const float4 wv = w4[t * 192 + i * 16 + l];
#pragma unroll
            for (int k = 0; k < 8; ++k)
                acc[t][k] = fmaf(xv[k].x, wv.x, fmaf(xv[k].y, wv.y,
                            fmaf(xv[k].z, wv.z, fmaf(xv[k].w, wv.w, acc[t][k]))));
        }
    }

#pragma unroll
    for (int k = 0; k < 8; ++k) {                         // k compile-time
        __syncthreads();
#pragma unroll
        for (int t = 0; t < Tsz; ++t) part[(p * Tsz + t) * PSTR + l] = acc[t][k];
        __syncthreads();
        if (tid < 16 * Tsz) {
            const int pq = tid / Tsz, t = tid - pq * Tsz;
            float s = bias[t];
#pragma unroll
            for (int l2 = 0; l2 < 16; ++l2) s += part[(pq * Tsz + t) * PSTR + l2];
            em[(pos0 + (size_t)k * 16 + pq) * Tsz + t] = s;
        }
    }
}

// ---------------- K2: chunk transfer matrices, column-parallel ----------------
// Row-task rho = (bc2, a): 9 lanes, lane j holds scalar pp = M[a][j] and the
// 9-float transition COLUMN j in regs. Step = 9 shfl + 9 fma/fmax. No thread
// holds more than ~12 floats of matrix state -> no promotion gamble.
__global__ __launch_bounds__(256, 1) void scan_kernel(
    const float* __restrict__ em, const int* __restrict__ mask,
    const float* __restrict__ trans, float* __restrict__ R2,
    float* __restrict__ MV) {
    __shared__ float Tlds[81];
    __shared__ float Elds[81];
    const int tid = threadIdx.x;
    if (tid < 81) {
        const float t = trans[tid];
        Tlds[tid] = t;
        Elds[tid] = exp2f(t * LOG2E);
    }
    __syncthreads();

    const int wid = tid >> 6, ln = tid & 63;
    const int q = ln / 9;                    // 0..7 (q==7 -> idle lane 63)
    const int j = ln - q * 9;
    const int W = blockIdx.x * 4 + wid;
    const int rho = W * 7 + q;               // row-task id
    if (q >= 7 || rho >= 2048 * Tsz) return;

    const int a = rho % Tsz;
    const int bc2 = rho / Tsz;               // 0..2047
    const bool isLSE = bc2 < 1024;
    const int bc = isLSE ? bc2 : bc2 - 1024;
    const int b = bc >> 4, c = bc & 15;
    const int lb = 9 * q;                    // group base lane in wave

    const float* emb = em + (size_t)b * Ssz * Tsz;
    const int* mkb = mask + b * Ssz;
    const int s_lo = c * 32 + 1;
    const int s_hi = min(c * 32 + 32, Ssz - 1);

    float ec = emb[s_lo * Tsz + j];
    int mc = mkb[s_lo];

    if (isLSE) {
        float Ecol[Tsz];
#pragma unroll
        for (int i = 0; i < Tsz; ++i) Ecol[i] = Elds[i * Tsz + j];
        float pp = (j == a) ? 1.0f : 0.0f;
        float K = 0.0f;
        for (int s = s_lo; s <= s_hi; ++s) {
            const int sp = (s < s_hi) ? s + 1 : s;
            const float en = emb[sp * Tsz + j];
            const int mn = mkb[sp];
            float g = __shfl(pp, lb, 64) * Ecol[0];
#pragma unroll
            for (int i = 1; i < Tsz; ++i)
                g = fmaf(__shfl(pp, lb + i, 64), Ecol[i], g);
            const float np = g * exp2f(ec * LOG2E);
            if (mc > 0) pp = np;
            if (((s - s_lo) & 7) == 7) {
                float ss = __shfl(pp, lb, 64);
#pragma unroll
                for (int i = 1; i < Tsz; ++i) ss += __shfl(pp, lb + i, 64);
                K += __log2f(ss);
                const float inv = 1.0f / ss;
                pp *= inv;
            }
            ec = en; mc = mn;
        }
        R2[((size_t)bc * Tsz + a) * Tsz + j] = K + __log2f(pp);
    } else {
        float Tcol[Tsz];
#pragma unroll
        for (int i = 0; i < Tsz; ++i) Tcol[i] = Tlds[i * Tsz + j];
        float pp = (j == a) ? 0.0f : -1e30f;
        for (int s = s_lo; s <= s_hi; ++s) {
            const int sp = (s < s_hi) ? s + 1 : s;
            const float en = emb[sp * Tsz + j];
            const int mn = mkb[sp];
            float g = __shfl(pp, lb, 64) + Tcol[0];
#pragma unroll
            for (int i = 1; i < Tsz; ++i)
                g = fmaxf(g, __shfl(pp, lb + i, 64) + Tcol[i]);
            if (mc > 0) pp = g + ec;
            ec = en; mc = mn;
        }
        MV[(size_t)bc * 81 + a * Tsz + j] = pp;
    }
}

// first-max argmax of 9 values (strict > keeps FIRST max)
__device__ __forceinline__ void amax9(const float (&v)[Tsz], float& bv, int& bi) {
    float w01v = (v[1] > v[0]) ? v[1] : v[0]; int w01i = (v[1] > v[0]) ? 1 : 0;
    float w23v = (v[3] > v[2]) ? v[3] : v[2]; int w23i = (v[3] > v[2]) ? 3 : 2;
    float w45v = (v[5] > v[4]) ? v[5] : v[4]; int w45i = (v[5] > v[4]) ? 5 : 4;
    float w67v = (v[7] > v[6]) ? v[7] : v[6]; int w67i = (v[7] > v[6]) ? 7 : 6;
    float x03v = (w23v > w01v) ? w23v : w01v; int x03i = (w23v > w01v) ? w23i : w01i;
    float x47v = (w67v > w45v) ? w67v : w45v; int x47i = (w67v > w45v) ? w67i : w45i;
    float y07v = (x47v > x03v) ? x47v : x03v; int y07i = (x47v > x03v) ? x47i : x03i;
    bv = (v[8] > y07v) ? v[8] : y07v;
    bi = (v[8] > y07v) ? 8 : y07i;
}

// ============ K3: per-batch finish + fused final reduce (last block) ============
__global__ __launch_bounds__(192, 1) void vit3_kernel(
    const float* __restrict__ em, const int* __restrict__ labels,
    const int* __restrict__ mask, const int* __restrict__ lengths,
    const float* __restrict__ start_t, const float* __restrict__ end_t,
    const float* __restrict__ trans, const float* __restrict__ R2,
    const float* __restrict__ MV, float* __restrict__ out_path,
    float* __restrict__ ll, float* __restrict__ dout, int* __restrict__ cnt) {
    __shared__ __align__(16) float em_s[4640];          // skewed [s][j]
    __shared__ __align__(16) int   mk_s[Ssz];
    __shared__ __align__(16) float mv_s[NCH * 81];
    __shared__ __align__(16) float r2_s[NCH * 81];
    __shared__ float tr_s[81];
    __shared__ float st_s[12], en_s[12];
    __shared__ __align__(16) float alc[2][NCH][12];
    __shared__ float a2c[2][12];
    __shared__ unsigned char bp[(Ssz - 1) * Tsz];
    __shared__ unsigned char mapA[64][12], mapB[64][12];
    __shared__ float den_sh, num_sh;
    __shared__ int lastf;

    const int b = blockIdx.x, tid = threadIdx.x;
    const int wv = tid >> 6, ln = tid & 63;
    const int c = tid / 12, j9 = tid % 12;
    const float* emb = em + (size_t)b * Ssz * Tsz;
    const int* mkb = mask + b * Ssz;
    const int* lbb = labels + b * Ssz;

    for (int i = tid; i < Ssz * Tsz; i += 192) {
        const int s = i / 9, j = i - s * 9;
        em_s[SK(s) + j] = emb[i];
    }
    for (int i = tid; i < Ssz; i += 192) mk_s[i] = mkb[i];
    {
        const float4* v4 = reinterpret_cast<const float4*>(MV + (size_t)b * NCH * 81);
        float4* vd = reinterpret_cast<float4*>(mv_s);
        for (int i = tid; i < NCH * 81 / 4; i += 192) vd[i] = v4[i];
        const float4* r4 = reinterpret_cast<const float4*>(R2 + (size_t)b * NCH * 81);
        float4* rd = reinterpret_cast<float4*>(r2_s);
        for (int i = tid; i < NCH * 81 / 4; i += 192) rd[i] = r4[i];
        if (tid < 81) tr_s[tid] = trans[tid];
        if (tid >= 96 && tid < 96 + Tsz) {
            st_s[tid - 96] = start_t[tid - 96];
            en_s[tid - 96] = end_t[tid - 96];
        }
    }
    __syncthreads();

    float tc[Tsz];
    const int jj = (j9 < Tsz) ? j9 : Tsz - 1;
#pragma unroll
    for (int i = 0; i < Tsz; ++i) tc[i] = tr_s[i * Tsz + jj];

    float aj = 0.0f;
    if (c == 0 && j9 < Tsz) {
        aj = st_s[j9] + em_s[j9];
        alc[0][0][j9] = aj;
    }
    if (wv == 1 && ln < Tsz) a2c[0][ln] = (st_s[ln] + em_s[ln]) * LOG2E;

    for (int r = 0; r < NCH; ++r) {
        __syncthreads();
        if (r < NCH - 1 && c == r + 1 && j9 < Tsz) {
            const float* M = &mv_s[r * 81];
            float m = alc[0][r][0] + M[j9];
#pragma unroll
            for (int i = 1; i < Tsz; ++i)
                m = fmaxf(m, alc[0][r][i] + M[i * Tsz + j9]);
            aj = m;
            alc[0][c][j9] = m;
        }
        if (wv == 1 && ln < Tsz) {
            const float* Rr = &r2_s[r * 81];
            float xi[Tsz];
#pragma unroll
            for (int i = 0; i < Tsz; ++i) xi[i] = a2c[r & 1][i] + Rr[i * Tsz + ln];
            float m = xi[0];
#pragma unroll
            for (int i = 1; i < Tsz; ++i) m = fmaxf(m, xi[i]);
            float sm = 0.0f;
#pragma unroll
            for (int i = 0; i < Tsz; ++i) sm += exp2f(xi[i] - m);
            a2c[(r + 1) & 1][ln] = m + __log2f(sm);
        }
    }

    int pb = 0;
    for (int k = 0; k < 32; ++k) {
        __syncthreads();
        const int s = c * 32 + 1 + k;
        if (j9 < Tsz && s <= Ssz - 1) {
            const int mk = mk_s[s];
            float av[12];
            const float4* ap = reinterpret_cast<const float4*>(&alc[pb][c][0]);
            *reinterpret_cast<float4*>(&av[0]) = ap[0];
            *reinterpret_cast<float4*>(&av[4]) = ap[1];
            *reinterpret_cast<float4*>(&av[8]) = ap[2];
            float v[Tsz];
#pragma unroll
            for (int i = 0; i < Tsz; ++i) v[i] = av[i] + tc[i];
            float bv; int bi;
            amax9(v, bv, bi);
            bp[(s - 1) * Tsz + j9] = (unsigned char)((mk > 0) ? bi : j9);
            if (mk > 0) aj = bv + em_s[SK(s) + j9];
        }
        if (j9 < Tsz) alc[1 - pb][c][j9] = aj;
        pb ^= 1;
    }
    __syncthreads();

    float bb = alc[0][NCH - 1][0] + en_s[0];
    int last = 0;
#pragma unroll
    for (int q = 1; q < Tsz; ++q) {
        const float qq = alc[0][NCH - 1][q] + en_s[q];
        if (qq > bb) { bb = qq; last = q; }
    }

    const int lo = ln * 8;
    const int hi = min(lo + 7, Ssz - 2);
    if (wv == 0) {
        int xf[Tsz];
#pragma unroll
        for (int t = 0; t < Tsz; ++t) xf[t] = t;
        for (int k = hi; k >= lo; --k) {
#pragma unroll
            for (int t = 0; t < Tsz; ++t) xf[t] = bp[k * Tsz + xf[t]];
        }
#pragma unroll
        for (int t = 0; t < Tsz; ++t) mapA[ln][t] = (unsigned char)xf[t];
    } else if (wv == 1) {
        if (ln == 0) {
            float xv[Tsz];
#pragma unroll
            for (int i = 0; i < Tsz; ++i) xv[i] = a2c[0][i] + en_s[i] * LOG2E;
            float m = xv[0];
#pragma unroll
            for (int i = 1; i < Tsz; ++i) m = fmaxf(m, xv[i]);
            float sm = 0.0f;
#pragma unroll
            for (int i = 0; i < Tsz; ++i) sm += exp2f(xv[i] - m);
            den_sh = m + __log2f(sm);
        }
    } else {
        float part = 0.0f;
        for (int s = 1 + ln; s < Ssz; s += 64) {
            if (mk_s[s] > 0) {
                const int tg = lbb[s];
                int pq = s - 1;
                while (pq > 0 && mk_s[pq] == 0) --pq;
                part += tr_s[lbb[pq] * Tsz + tg] + em_s[SK(s) + tg];
            }
        }
#pragma unroll
        for (int off = 32; off >= 1; off >>= 1) part += __shfl_xor(part, off, 64);
        if (ln == 0) {
            const int tg0 = lbb[0];
            float num = part + st_s[tg0] + em_s[tg0];
            int pq = Ssz - 1;
            while (pq > 0 && mk_s[pq] == 0) --pq;
            num += en_s[lbb[pq]];
            num_sh = num;
        }
    }

#define VIT_RND(CUR, NXT, D)                                               \
    {                                                                      \
        unsigned char nn[Tsz];                                             \
        if (wv == 0) {                                                     \
            const int o = ln + (D);                                        \
            if (o < 64) {                                                  \
                _Pragma("unroll") for (int t = 0; t < Tsz; ++t)            \
                    nn[t] = CUR[ln][CUR[o][t]];                            \
            } else {                                                       \
                _Pragma("unroll") for (int t = 0; t < Tsz; ++t)            \
                    nn[t] = CUR[ln][t];                                    \
            }                                                              \
        }                                                                  \
        __syncthreads();                                                   \
        if (wv == 0) {                                                     \
            _Pragma("unroll") for (int t = 0; t < Tsz; ++t)                \
                NXT[ln][t] = nn[t];                                        \
        }                                                                  \
        __syncthreads();                                                   \
    }
    VIT_RND(mapA, mapB, 1)
    VIT_RND(mapB, mapA, 2)
    VIT_RND(mapA, mapB, 4)
    VIT_RND(mapB, mapA, 8)
    VIT_RND(mapA, mapB, 16)
    VIT_RND(mapB, mapA, 32)
#undef VIT_RND

    if (wv == 0) {
        int t = (ln == 63) ? last : (int)mapA[ln + 1][last];
        float* op = out_path + (size_t)b * Ssz;
        for (int k = hi; k >= lo; --k) {
            t = bp[k * Tsz + t];
            op[k] = (float)t;
        }
        if (ln == 0) op[Ssz - 1] = (float)last;
    }
    if (b == 0 && wv == 2) dout[1 + Bsz * Ssz + ln] = (float)lengths[ln];

    if (tid == 0) {
        ll[b] = num_sh - den_sh * LN2F;
        __threadfence();
        lastf = (atomicAdd(cnt, 1) == Bsz - 1) ? 1 : 0;
    }
    __syncthreads();
    if (lastf && wv == 0) {
        __threadfence();
        float v = ll[ln];
#pragma unroll
        for (int off = 32; off >= 1; off >>= 1) v += __shfl_xor(v, off, 64);
        if (ln == 0) dout[0] = -v * (1.0f / (float)Bsz);
    }
}

extern "C" void kernel_launch(void* const* d_in, const int* in_sizes, int n_in,
                              void* d_out, int out_size, void* d_ws, size_t ws_size,
                              hipStream_t stream) {
    const float* enc    = (const float*)d_in[0];
    const int*   labels = (const int*)d_in[1];
    const int*   mask   = (const int*)d_in[2];
    const int*   lengths= (const int*)d_in[3];
    const float* fcw    = (const float*)d_in[4];
    const float* fcb    = (const float*)d_in[5];
    const float* startt = (const float*)d_in[6];
    const float* endt   = (const float*)d_in[7];
    const float* trans  = (const float*)d_in[8];

    float* out = (float*)d_out;
    float* em  = (float*)d_ws;                                // 294912 f
    float* R2  = em + (size_t)Bsz * Ssz * Tsz;                // 82944 f
    float* MV  = R2 + (size_t)Bsz * NCH * 81;                 // 82944 f
    float* ll  = MV + (size_t)Bsz * NCH * 81;                 // 64 f
    int*   cnt = (int*)(ll + Bsz);                            // 1 int

    emis_kernel<<<Bsz * Ssz / 128, 256, 0, stream>>>(enc, fcw, fcb, em, cnt);
    const int row_tasks = 2 * Bsz * NCH * Tsz;                // 18432
    scan_kernel<<<(row_tasks + 27) / 28, 256, 0, stream>>>(em, mask, trans, R2, MV);
    vit3_kernel<<<Bsz, 192, 0, stream>>>(em, labels, mask, lengths, startt, endt,
                                         trans, R2, MV, out + 1, ll, out, cnt);
}

// Round 9
// 65.866 us; speedup vs baseline: 1.4533x; 1.1667x over previous
//
#include <hip/hip_runtime.h>

#define Bsz 64
#define Ssz 512
#define Hsz 768
#define Tsz 9
#define NCH 16
#define LOG2E 1.4426950408889634f
#define LN2F  0.6931471805599453f
#define PSTR 17

__device__ __forceinline__ int SK(int s) { return s * Tsz + ((s >> 5) << 1); }

// ---------------- K1: emissions = enc @ fc_w^T + fc_b ----------------
// 1024 blocks x 256 threads; 32 positions/block, 2 positions/thread.
// 4 blocks/CU (LDS-capped) = 16 waves/CU: enough TLP to stream HBM, while
// each w-tile ds_read feeds 2 positions (halves r2's LDS-pipe pressure).
__global__ __launch_bounds__(256, 1) void emis_kernel(
    const float* __restrict__ x, const float* __restrict__ fcw,
    const float* __restrict__ fcb, float* __restrict__ em,
    int* __restrict__ cnt) {
    __shared__ __align__(16) float4 w4[Tsz * Hsz / 4];   // 27648 B
    __shared__ float bias[Tsz];
    __shared__ float part[16 * Tsz * PSTR];              // 9792 B
    const int tid = threadIdx.x;
    if (blockIdx.x == 0 && tid == 0) *cnt = 0;           // vit3's reduce counter
    const float4* fw4 = reinterpret_cast<const float4*>(fcw);
#pragma unroll
    for (int i = 0; i < 7; ++i) {
        const int o = tid + i * 256;
        if (o < 1728) w4[o] = fw4[o];
    }
    if (tid < Tsz) bias[tid] = fcb[tid];
    __syncthreads();

    const int p = tid >> 4, l = tid & 15;
    const size_t pos0 = (size_t)blockIdx.x * 32;
    const float4* xr0 = reinterpret_cast<const float4*>(x + (pos0 + p) * Hsz);
    const float4* xr1 = reinterpret_cast<const float4*>(x + (pos0 + 16 + p) * Hsz);

    float acc[Tsz][2];
#pragma unroll
    for (int t = 0; t < Tsz; ++t) { acc[t][0] = 0.0f; acc[t][1] = 0.0f; }

#pragma unroll 4
    for (int i = 0; i < 12; ++i) {
        const float4 xv0 = xr0[i * 16 + l];
        const float4 xv1 = xr1[i * 16 + l];
#pragma unroll
        for (int t = 0; t < Tsz; ++t) {
            const float4 wv = w4[t * 192 + i * 16 + l];
            acc[t][0] = fmaf(xv0.x, wv.x, fmaf(xv0.y, wv.y,
                        fmaf(xv0.z, wv.z, fmaf(xv0.w, wv.w, acc[t][0]))));
            acc[t][1] = fmaf(xv1.x, wv.x, fmaf(xv1.y, wv.y,
                        fmaf(xv1.z, wv.z, fmaf(xv1.w, wv.w, acc[t][1]))));
        }
    }

#pragma unroll
    for (int k = 0; k < 2; ++k) {                        // k compile-time
        __syncthreads();
#pragma unroll
        for (int t = 0; t < Tsz; ++t) part[(p * Tsz + t) * PSTR + l] = acc[t][k];
        __syncthreads();
        if (tid < 16 * Tsz) {
            const int pq = tid / Tsz, t = tid - pq * Tsz;
            float s = bias[t];
#pragma unroll
            for (int l2 = 0; l2 < 16; ++l2) s += part[(pq * Tsz + t) * PSTR + l2];
            em[(pos0 + (size_t)k * 16 + pq) * Tsz + t] = s;
        }
    }
}

// ---------------- K2: chunk transfer matrices, column-parallel ----------------
// Row-task rho = (bc2, a): 9 lanes, lane j holds scalar pp = M[a][j] and the
// 9-float transition COLUMN j in regs. Step = 9 shfl + 9 fma/fmax.
__global__ __launch_bounds__(256, 1) void scan_kernel(
    const float* __restrict__ em, const int* __restrict__ mask,
    const float* __restrict__ trans, float* __restrict__ R2,
    float* __restrict__ MV) {
    __shared__ float Tlds[81];
    __shared__ float Elds[81];
    const int tid = threadIdx.x;
    if (tid < 81) {
        const float t = trans[tid];
        Tlds[tid] = t;
        Elds[tid] = exp2f(t * LOG2E);
    }
    __syncthreads();

    const int wid = tid >> 6, ln = tid & 63;
    const int q = ln / 9;                    // 0..7 (q==7 -> idle lane 63)
    const int j = ln - q * 9;
    const int W = blockIdx.x * 4 + wid;
    const int rho = W * 7 + q;               // row-task id
    if (q >= 7 || rho >= 2048 * Tsz) return;

    const int a = rho % Tsz;
    const int bc2 = rho / Tsz;               // 0..2047
    const bool isLSE = bc2 < 1024;
    const int bc = isLSE ? bc2 : bc2 - 1024;
    const int b = bc >> 4, c = bc & 15;
    const int lb = 9 * q;                    // group base lane in wave

    const float* emb = em + (size_t)b * Ssz * Tsz;
    const int* mkb = mask + b * Ssz;
    const int s_lo = c * 32 + 1;
    const int s_hi = min(c * 32 + 32, Ssz - 1);

    float ec = emb[s_lo * Tsz + j];
    int mc = mkb[s_lo];

    if (isLSE) {
        float Ecol[Tsz];
#pragma unroll
        for (int i = 0; i < Tsz; ++i) Ecol[i] = Elds[i * Tsz + j];
        float pp = (j == a) ? 1.0f : 0.0f;
        float K = 0.0f;
        for (int s = s_lo; s <= s_hi; ++s) {
            const int sp = (s < s_hi) ? s + 1 : s;
            const float en = emb[sp * Tsz + j];
            const int mn = mkb[sp];
            float g = __shfl(pp, lb, 64) * Ecol[0];
#pragma unroll
            for (int i = 1; i < Tsz; ++i)
                g = fmaf(__shfl(pp, lb + i, 64), Ecol[i], g);
            const float np = g * exp2f(ec * LOG2E);
            if (mc > 0) pp = np;
            if (((s - s_lo) & 7) == 7) {
                float ss = __shfl(pp, lb, 64);
#pragma unroll
                for (int i = 1; i < Tsz; ++i) ss += __shfl(pp, lb + i, 64);
                K += __log2f(ss);
                const float inv = 1.0f / ss;
                pp *= inv;
            }
            ec = en; mc = mn;
        }
        R2[((size_t)bc * Tsz + a) * Tsz + j] = K + __log2f(pp);
    } else {
        float Tcol[Tsz];
#pragma unroll
        for (int i = 0; i < Tsz; ++i) Tcol[i] = Tlds[i * Tsz + j];
        float pp = (j == a) ? 0.0f : -1e30f;
        for (int s = s_lo; s <= s_hi; ++s) {
            const int sp = (s < s_hi) ? s + 1 : s;
            const float en = emb[sp * Tsz + j];
            const int mn = mkb[sp];
            float g = __shfl(pp, lb, 64) + Tcol[0];
#pragma unroll
            for (int i = 1; i < Tsz; ++i)
                g = fmaxf(g, __shfl(pp, lb + i, 64) + Tcol[i]);
            if (mc > 0) pp = g + ec;
            ec = en; mc = mn;
        }
        MV[(size_t)bc * 81 + a * Tsz + j] = pp;
    }
}

// first-max argmax of 9 values (strict > keeps FIRST max)
__device__ __forceinline__ void amax9(const float (&v)[Tsz], float& bv, int& bi) {
    float w01v = (v[1] > v[0]) ? v[1] : v[0]; int w01i = (v[1] > v[0]) ? 1 : 0;
    float w23v = (v[3] > v[2]) ? v[3] : v[2]; int w23i = (v[3] > v[2]) ? 3 : 2;
    float w45v = (v[5] > v[4]) ? v[5] : v[4]; int w45i = (v[5] > v[4]) ? 5 : 4;
    float w67v = (v[7] > v[6]) ? v[7] : v[6]; int w67i = (v[7] > v[6]) ? 7 : 6;
    float x03v = (w23v > w01v) ? w23v : w01v; int x03i = (w23v > w01v) ? w23i : w01i;
    float x47v = (w67v > w45v) ? w67v : w45v; int x47i = (w67v > w45v) ? w67i : w45i;
    float y07v = (x47v > x03v) ? x47v : x03v; int y07i = (x47v > x03v) ? x47i : x03i;
    bv = (v[8] > y07v) ? v[8] : y07v;
    bi = (v[8] > y07v) ? 8 : y07i;
}

// ============ K3: per-batch finish + fused final reduce (last block) ============
__global__ __launch_bounds__(192, 1) void vit3_kernel(
    const float* __restrict__ em, const int* __restrict__ labels,
    const int* __restrict__ mask, const int* __restrict__ lengths,
    const float* __restrict__ start_t, const float* __restrict__ end_t,
    const float* __restrict__ trans, const float* __restrict__ R2,
    const float* __restrict__ MV, float* __restrict__ out_path,
    float* __restrict__ ll, float* __restrict__ dout, int* __restrict__ cnt) {
    __shared__ __align__(16) float em_s[4640];          // skewed [s][j]
    __shared__ __align__(16) int   mk_s[Ssz];
    __shared__ __align__(16) float mv_s[NCH * 81];
    __shared__ __align__(16) float r2_s[NCH * 81];
    __shared__ float tr_s[81];
    __shared__ float st_s[12], en_s[12];
    __shared__ __align__(16) float alc[2][NCH][12];
    __shared__ float a2c[2][12];
    __shared__ unsigned char bp[(Ssz - 1) * Tsz];
    __shared__ unsigned char mapA[64][12], mapB[64][12];
    __shared__ float den_sh, num_sh;
    __shared__ int lastf;

    const int b = blockIdx.x, tid = threadIdx.x;
    const int wv = tid >> 6, ln = tid & 63;
    const int c = tid / 12, j9 = tid % 12;
    const float* emb = em + (size_t)b * Ssz * Tsz;
    const int* mkb = mask + b * Ssz;
    const int* lbb = labels + b * Ssz;

    for (int i = tid; i < Ssz * Tsz; i += 192) {
        const int s = i / 9, j = i - s * 9;
        em_s[SK(s) + j] = emb[i];
    }
    for (int i = tid; i < Ssz; i += 192) mk_s[i] = mkb[i];
    {
        const float4* v4 = reinterpret_cast<const float4*>(MV + (size_t)b * NCH * 81);
        float4* vd = reinterpret_cast<float4*>(mv_s);
        for (int i = tid; i < NCH * 81 / 4; i += 192) vd[i] = v4[i];
        const float4* r4 = reinterpret_cast<const float4*>(R2 + (size_t)b * NCH * 81);
        float4* rd = reinterpret_cast<float4*>(r2_s);
        for (int i = tid; i < NCH * 81 / 4; i += 192) rd[i] = r4[i];
        if (tid < 81) tr_s[tid] = trans[tid];
        if (tid >= 96 && tid < 96 + Tsz) {
            st_s[tid - 96] = start_t[tid - 96];
            en_s[tid - 96] = end_t[tid - 96];
        }
    }
    __syncthreads();

    float tc[Tsz];
    const int jj = (j9 < Tsz) ? j9 : Tsz - 1;
#pragma unroll
    for (int i = 0; i < Tsz; ++i) tc[i] = tr_s[i * Tsz + jj];

    float aj = 0.0f;
    if (c == 0 && j9 < Tsz) {
        aj = st_s[j9] + em_s[j9];
        alc[0][0][j9] = aj;
    }
    if (wv == 1 && ln < Tsz) a2c[0][ln] = (st_s[ln] + em_s[ln]) * LOG2E;

    for (int r = 0; r < NCH; ++r) {
        __syncthreads();
        if (r < NCH - 1 && c == r + 1 && j9 < Tsz) {
            const float* M = &mv_s[r * 81];
            float m = alc[0][r][0] + M[j9];
#pragma unroll
            for (int i = 1; i < Tsz; ++i)
                m = fmaxf(m, alc[0][r][i] + M[i * Tsz + j9]);
            aj = m;
            alc[0][c][j9] = m;
        }
        if (wv == 1 && ln < Tsz) {
            const float* Rr = &r2_s[r * 81];
            float xi[Tsz];
#pragma unroll
            for (int i = 0; i < Tsz; ++i) xi[i] = a2c[r & 1][i] + Rr[i * Tsz + ln];
            float m = xi[0];
#pragma unroll
            for (int i = 1; i < Tsz; ++i) m = fmaxf(m, xi[i]);
            float sm = 0.0f;
#pragma unroll
            for (int i = 0; i < Tsz; ++i) sm += exp2f(xi[i] - m);
            a2c[(r + 1) & 1][ln] = m + __log2f(sm);
        }
    }

    int pb = 0;
    for (int k = 0; k < 32; ++k) {
        __syncthreads();
        const int s = c * 32 + 1 + k;
        if (j9 < Tsz && s <= Ssz - 1) {
            const int mk = mk_s[s];
            float av[12];
            const float4* ap = reinterpret_cast<const float4*>(&alc[pb][c][0]);
            *reinterpret_cast<float4*>(&av[0]) = ap[0];
            *reinterpret_cast<float4*>(&av[4]) = ap[1];
            *reinterpret_cast<float4*>(&av[8]) = ap[2];
            float v[Tsz];
#pragma unroll
            for (int i = 0; i < Tsz; ++i) v[i] = av[i] + tc[i];
            float bv; int bi;
            amax9(v, bv, bi);
            bp[(s - 1) * Tsz + j9] = (unsigned char)((mk > 0) ? bi : j9);
            if (mk > 0) aj = bv + em_s[SK(s) + j9];
        }
        if (j9 < Tsz) alc[1 - pb][c][j9] = aj;
        pb ^= 1;
    }
    __syncthreads();

    float bb = alc[0][NCH - 1][0] + en_s[0];
    int last = 0;
#pragma unroll
    for (int q = 1; q < Tsz; ++q) {
        const float qq = alc[0][NCH - 1][q] + en_s[q];
        if (qq > bb) { bb = qq; last = q; }
    }

    const int lo = ln * 8;
    const int hi = min(lo + 7, Ssz - 2);
    if (wv == 0) {
        int xf[Tsz];
#pragma unroll
        for (int t = 0; t < Tsz; ++t) xf[t] = t;
        for (int k = hi; k >= lo; --k) {
#pragma unroll
            for (int t = 0; t < Tsz; ++t) xf[t] = bp[k * Tsz + xf[t]];
        }
#pragma unroll
        for (int t = 0; t < Tsz; ++t) mapA[ln][t] = (unsigned char)xf[t];
    } else if (wv == 1) {
        if (ln == 0) {
            float xv[Tsz];
#pragma unroll
            for (int i = 0; i < Tsz; ++i) xv[i] = a2c[0][i] + en_s[i] * LOG2E;
            float m = xv[0];
#pragma unroll
            for (int i = 1; i < Tsz; ++i) m = fmaxf(m, xv[i]);
            float sm = 0.0f;
#pragma unroll
            for (int i = 0; i < Tsz; ++i) sm += exp2f(xv[i] - m);
            den_sh = m + __log2f(sm);
        }
    } else {
        float part = 0.0f;
        for (int s = 1 + ln; s < Ssz; s += 64) {
            if (mk_s[s] > 0) {
                const int tg = lbb[s];
                int pq = s - 1;
                while (pq > 0 && mk_s[pq] == 0) --pq;
                part += tr_s[lbb[pq] * Tsz + tg] + em_s[SK(s) + tg];
            }
        }
#pragma unroll
        for (int off = 32; off >= 1; off >>= 1) part += __shfl_xor(part, off, 64);
        if (ln == 0) {
            const int tg0 = lbb[0];
            float num = part + st_s[tg0] + em_s[tg0];
            int pq = Ssz - 1;
            while (pq > 0 && mk_s[pq] == 0) --pq;
            num += en_s[lbb[pq]];
            num_sh = num;
        }
    }

#define VIT_RND(CUR, NXT, D)                                               \
    {                                                                      \
        unsigned char nn[Tsz];                                             \
        if (wv == 0) {                                                     \
            const int o = ln + (D);                                        \
            if (o < 64) {                                                  \
                _Pragma("unroll") for (int t = 0; t < Tsz; ++t)            \
                    nn[t] = CUR[ln][CUR[o][t]];                            \
            } else {                                                       \
                _Pragma("unroll") for (int t = 0; t < Tsz; ++t)            \
                    nn[t] = CUR[ln][t];                                    \
            }                                                              \
        }                                                                  \
        __syncthreads();                                                   \
        if (wv == 0) {                                                     \
            _Pragma("unroll") for (int t = 0; t < Tsz; ++t)                \
                NXT[ln][t] = nn[t];                                        \
        }                                                                  \
        __syncthreads();                                                   \
    }
    VIT_RND(mapA, mapB, 1)
    VIT_RND(mapB, mapA, 2)
    VIT_RND(mapA, mapB, 4)
    VIT_RND(mapB, mapA, 8)
    VIT_RND(mapA, mapB, 16)
    VIT_RND(mapB, mapA, 32)
#undef VIT_RND

    if (wv == 0) {
        int t = (ln == 63) ? last : (int)mapA[ln + 1][last];
        float* op = out_path + (size_t)b * Ssz;
        for (int k = hi; k >= lo; --k) {
            t = bp[k * Tsz + t];
            op[k] = (float)t;
        }
        if (ln == 0) op[Ssz - 1] = (float)last;
    }
    if (b == 0 && wv == 2) dout[1 + Bsz * Ssz + ln] = (float)lengths[ln];

    if (tid == 0) {
        ll[b] = num_sh - den_sh * LN2F;
        __threadfence();
        lastf = (atomicAdd(cnt, 1) == Bsz - 1) ? 1 : 0;
    }
    __syncthreads();
    if (lastf && wv == 0) {
        __threadfence();
        float v = ll[ln];
#pragma unroll
        for (int off = 32; off >= 1; off >>= 1) v += __shfl_xor(v, off, 64);
        if (ln == 0) dout[0] = -v * (1.0f / (float)Bsz);
    }
}

extern "C" void kernel_launch(void* const* d_in, const int* in_sizes, int n_in,
                              void* d_out, int out_size, void* d_ws, size_t ws_size,
                              hipStream_t stream) {
    const float* enc    = (const float*)d_in[0];
    const int*   labels = (const int*)d_in[1];
    const int*   mask   = (const int*)d_in[2];
    const int*   lengths= (const int*)d_in[3];
    const float* fcw    = (const float*)d_in[4];
    const float* fcb    = (const float*)d_in[5];
    const float* startt = (const float*)d_in[6];
    const float* endt   = (const float*)d_in[7];
    const float* trans  = (const float*)d_in[8];

    float* out = (float*)d_out;
    float* em  = (float*)d_ws;                                // 294912 f
    float* R2  = em + (size_t)Bsz * Ssz * Tsz;                // 82944 f
    float* MV  = R2 + (size_t)Bsz * NCH * 81;                 // 82944 f
    float* ll  = MV + (size_t)Bsz * NCH * 81;                 // 64 f
    int*   cnt = (int*)(ll + Bsz);                            // 1 int

    emis_kernel<<<Bsz * Ssz / 32, 256, 0, stream>>>(enc, fcw, fcb, em, cnt);
    const int row_tasks = 2 * Bsz * NCH * Tsz;                // 18432
    scan_kernel<<<(row_tasks + 27) / 28, 256, 0, stream>>>(em, mask, trans, R2, MV);
    vit3_kernel<<<Bsz, 192, 0, stream>>>(em, labels, mask, lengths, startt, endt,
                                         trans, R2, MV, out + 1, ll, out, cnt);
}